// Round 11
// baseline (9371.716 us; speedup 1.0000x reference)
//
#include <hip/hip_runtime.h>
#include <hip/hip_bf16.h>

#define BB 512
#define SS 256
#define HH 256
#define DD 64
#define TT 50
#define GG 1024   // 4*H
#define INW 129

typedef _Float16 h4 __attribute__((ext_vector_type(4)));
typedef _Float16 h8 __attribute__((ext_vector_type(8)));
typedef __fp16 hf2 __attribute__((ext_vector_type(2)));   // builtin-facing f16 pair
typedef float f32x4 __attribute__((ext_vector_type(4)));
typedef unsigned int u32;

__device__ inline float sigf(float x) { return 1.f / (1.f + __expf(-x)); }
__device__ inline float tanhf_(float x) { return 1.f - 2.f / (__expf(2.f * x) + 1.f); }

__device__ inline u32 pkrtz(float a, float b) {
    hf2 h = __builtin_amdgcn_cvt_pkrtz(a, b);
    return __builtin_bit_cast(u32, h);
}

// ============ prep: r5/r6 validated — Bhh split 4(AGPR)/2(LDS)/2(stream) ============
__global__ __launch_bounds__(256) void prep_kernel(
    const float* __restrict__ W_hh, const float* __restrict__ W_ih,
    const float* __restrict__ Wd1, const float* __restrict__ Wd2,
    h4* __restrict__ BhhV4, h4* __restrict__ BhhL4, h4* __restrict__ BhhS4,
    _Float16* __restrict__ Bih, h4* __restrict__ A1f4, h4* __restrict__ A2f4)
{
    int idx = blockIdx.x * 256 + threadIdx.x;
    if (idx < 65536) {
        int eh = idx & 1;
        int l = (idx >> 1) & 63;
        int ks = (idx >> 7) & 7;
        int s = (idx >> 10) & 7;
        int w = (idx >> 13) & 7;
        int g = s & 3, jt = s >> 2;
        int n = g * 256 + w * 32 + jt * 16 + (l & 15);
        int k = 32 * ks + 8 * (l >> 4) + 4 * eh;
        float4 v = *(const float4*)(W_hh + (size_t)n * HH + k);
        h4 o; o[0] = (_Float16)v.x; o[1] = (_Float16)v.y; o[2] = (_Float16)v.z; o[3] = (_Float16)v.w;
        if (ks < 4)      BhhV4[(((w * 8 + s) * 4 + ks) * 64 + l) * 2 + eh] = o;
        else if (ks < 6) BhhL4[(((w * 8 + s) * 2 + (ks - 4)) * 64 + l) * 2 + eh] = o;
        else             BhhS4[(((w * 8 + s) * 2 + (ks - 6)) * 64 + l) * 2 + eh] = o;
    } else if (idx < 106496) {
        int fj = idx - 65536;
        int eh = fj & 1;
        int l = (fj >> 1) & 63;
        int si = fj >> 7;              // [0,320) = ntile*5 + ks
        int ks = si % 5;
        int ntile = si / 5;
        int n = ntile * 16 + (l & 15);
        int k = 32 * ks + 8 * (l >> 4) + 4 * eh;
        h4 o;
#pragma unroll
        for (int i = 0; i < 4; i++) {
            int kk = k + i;
            o[i] = (_Float16)((kk < INW) ? W_ih[(size_t)n * INW + kk] : 0.f);
        }
        *(h4*)(Bih + (size_t)fj * 4) = o;
    } else if (idx < 110592) {
        int fj = idx - 106496;         // A1f
        int eh = fj & 1;
        int l = (fj >> 1) & 63;
        int slot = fj >> 7;            // t*2+ks
        int ks = slot & 1, t = slot >> 1;
        int row = 16 * t + (l & 15);
        int k = 32 * ks + 8 * (l >> 4) + 4 * eh;
        h4 o;
#pragma unroll
        for (int i = 0; i < 4; i++) o[i] = (_Float16)Wd1[(size_t)row * DD + k + i];
        A1f4[fj] = o;
    } else if (idx < 114688) {
        int fj = idx - 110592;         // A2f
        int eh = fj & 1;
        int l = (fj >> 1) & 63;
        int slot = fj >> 7;            // t2*8+ks
        int ks = slot & 7, t2 = slot >> 3;
        int row = 16 * t2 + (l & 15);
        int k = 32 * ks + 8 * (l >> 4) + 4 * eh;
        h4 o;
#pragma unroll
        for (int i = 0; i < 4; i++) o[i] = (_Float16)Wd2[(size_t)row * HH + k + i];
        A2f4[fj] = o;
    }
}

// ============ xw GEMM (MFMA): validated r5 version (8-wave slot mapping) ============
__global__ __launch_bounds__(256) void xw_kernel(
    const float* __restrict__ x, const _Float16* __restrict__ Bih,
    const float* __restrict__ b_ih, const float* __restrict__ b_hh,
    h4* __restrict__ xwf)
{
    __shared__ __align__(16) _Float16 ash[4][5][64][8];   // 20 KB, A-frag layout
    int tid = threadIdx.x;
    int w4 = tid >> 6, l = tid & 63;
    int bx = blockIdx.x;
    int t = bx >> 3, Bb = bx & 7;           // 64 batch-rows: b = Bb*64 + rr

    for (int i = tid; i < 64 * 160; i += 256) {
        int rr = i / 160, kk = i % 160;
        float v = (kk < INW) ? x[((size_t)(Bb * 64 + rr) * SS + t) * INW + kk] : 0.f;
        ash[rr >> 4][kk >> 5][(((kk & 31) >> 3) << 4) + (rr & 15)][kk & 7] = (_Float16)v;
    }
    __syncthreads();

    h8 A[4][5];
#pragma unroll
    for (int ms = 0; ms < 4; ms++)
#pragma unroll
        for (int ks = 0; ks < 5; ks++)
            A[ms][ks] = *(h8*)&ash[ms][ks][l][0];

    const h8* Bih8 = (const h8*)Bih;
    for (int nt16 = 0; nt16 < 16; nt16++) {
        int ntile = w4 * 16 + nt16;
        h8 Bv[5];
#pragma unroll
        for (int ks = 0; ks < 5; ks++) Bv[ks] = Bih8[(ntile * 5 + ks) * 64 + l];
        int nb = ntile * 16 + (l & 15);
        float bias = b_ih[nb] + b_hh[nb];
        f32x4 acc[4];
#pragma unroll
        for (int ms = 0; ms < 4; ms++) acc[ms] = (f32x4){0.f, 0.f, 0.f, 0.f};
#pragma unroll
        for (int ks = 0; ks < 5; ks++)
#pragma unroll
            for (int ms = 0; ms < 4; ms++)
                acc[ms] = __builtin_amdgcn_mfma_f32_16x16x32_f16(A[ms][ks], Bv[ks], acc[ms], 0, 0, 0);
        // slot for 8-wave LSTM: w = (ntile&15)>>1, jt = ntile&1, g = ntile>>4
        int slot = ((ntile & 15) >> 1) * 8 + (ntile & 1) * 4 + (ntile >> 4);
#pragma unroll
        for (int ms = 0; ms < 4; ms++) {
            int bg = Bb * 4 + ms;
            h4 o;
#pragma unroll
            for (int r = 0; r < 4; r++) o[r] = (_Float16)(acc[ms][r] + bias);
            xwf[(((size_t)bg * SS + t) * 64 + slot) * 64 + l] = o;
        }
    }
}

// ============ LSTM: exact round-5 kernel (measured 1108 us; register-feasible config) ============
__global__ __launch_bounds__(512, 2) void lstm_kernel(
    const h8* __restrict__ BhhV, const h8* __restrict__ BhhL, const h8* __restrict__ BhhS,
    const h4* __restrict__ xwf, const int* __restrict__ lengths, float* __restrict__ pooled)
{
    __shared__ __align__(16) _Float16 Wlds[65536];        // 128 KB: ks4-5 weight fragments
    __shared__ __align__(16) _Float16 hbuf[2][8][64][8];  // 16 KB double-buffered A-frag h
    int tid = threadIdx.x;
    int w = tid >> 6, l = tid & 63;
    int bg = blockIdx.x;

    {   // copy ks4-5 weights into LDS (linear, 128 KB)
        const uint4* src = (const uint4*)BhhL;
        uint4* dst = (uint4*)Wlds;
#pragma unroll
        for (int i = 0; i < 16; i++) dst[i * 512 + tid] = src[i * 512 + tid];
    }

    h8 Wv[8][4];
#pragma unroll
    for (int s = 0; s < 8; s++)
#pragma unroll
        for (int ks = 0; ks < 4; ks++)
            Wv[s][ks] = BhhV[((w * 8 + s) * 4 + ks) * 64 + l];

    int len_[4];
    float c_[2][4], pa[2][4];
#pragma unroll
    for (int r = 0; r < 4; r++) {
        int b = 4 * (l >> 4) + r;
        len_[r] = lengths[bg * 16 + b];
#pragma unroll
        for (int jt = 0; jt < 2; jt++) { c_[jt][r] = 0.f; pa[jt][r] = 0.f; }
    }

    {   // zero h buffers (h0 = 0): 1024 uint4, 2 per thread
        uint4* hz = (uint4*)hbuf;
        hz[tid] = make_uint4(0, 0, 0, 0);
        hz[512 + tid] = make_uint4(0, 0, 0, 0);
    }
    __syncthreads();

    int cur = 0;
    for (int t = 0; t < SS; t++) {
        const h4* xpb = xwf + (((size_t)bg * SS + t) * 64 + w * 8) * 64 + l;
        int zoff = 0;
        asm volatile("" : "+v"(zoff));            // block LICM: force per-step re-load of streamed weights
        const h8* bS = BhhS + zoff;
#pragma unroll
        for (int jt = 0; jt < 2; jt++) {
            h4 xv[4];
#pragma unroll
            for (int g = 0; g < 4; g++) xv[g] = xpb[(jt * 4 + g) * 64];
            h8 Ws[4];
#pragma unroll
            for (int g = 0; g < 4; g++) Ws[g] = bS[((w * 8 + jt * 4 + g) * 2 + 0) * 64 + l];
            f32x4 acc[4];
#pragma unroll
            for (int g = 0; g < 4; g++) acc[g] = (f32x4){0.f, 0.f, 0.f, 0.f};
            // ks 0-3 from VGPR/AGPR weights
#pragma unroll
            for (int ks = 0; ks < 4; ks++) {
                h8 A = *(const h8*)&hbuf[cur][ks][l][0];
#pragma unroll
                for (int g = 0; g < 4; g++)
                    acc[g] = __builtin_amdgcn_mfma_f32_16x16x32_f16(A, Wv[jt * 4 + g][ks], acc[g], 0, 0, 0);
            }
            // ks 6 (streamed, landed)
            {
                h8 A = *(const h8*)&hbuf[cur][6][l][0];
#pragma unroll
                for (int g = 0; g < 4; g++)
                    acc[g] = __builtin_amdgcn_mfma_f32_16x16x32_f16(A, Ws[g], acc[g], 0, 0, 0);
            }
            // reissue stream for ks 7 into same regs
#pragma unroll
            for (int g = 0; g < 4; g++) Ws[g] = bS[((w * 8 + jt * 4 + g) * 2 + 1) * 64 + l];
            // ks 4-5 from LDS
#pragma unroll
            for (int ks = 4; ks < 6; ks++) {
                h8 A = *(const h8*)&hbuf[cur][ks][l][0];
#pragma unroll
                for (int g = 0; g < 4; g++) {
                    h8 Bw = *(const h8*)&Wlds[(((w * 8 + jt * 4 + g) * 2 + (ks - 4)) * 64 + l) * 8];
                    acc[g] = __builtin_amdgcn_mfma_f32_16x16x32_f16(A, Bw, acc[g], 0, 0, 0);
                }
            }
            // ks 7
            {
                h8 A = *(const h8*)&hbuf[cur][7][l][0];
#pragma unroll
                for (int g = 0; g < 4; g++)
                    acc[g] = __builtin_amdgcn_mfma_f32_16x16x32_f16(A, Ws[g], acc[g], 0, 0, 0);
            }
            // gates + h update
#pragma unroll
            for (int r = 0; r < 4; r++) {
                float gi = acc[0][r] + (float)xv[0][r];
                float gf = acc[1][r] + (float)xv[1][r];
                float gg = acc[2][r] + (float)xv[2][r];
                float go = acc[3][r] + (float)xv[3][r];
                float cc = sigf(gf) * c_[jt][r] + sigf(gi) * tanhf_(gg);
                c_[jt][r] = cc;
                float hh = sigf(go) * tanhf_(cc);
                if (t < len_[r]) pa[jt][r] += hh;
                int b = 4 * (l >> 4) + r;
                int j = w * 32 + jt * 16 + (l & 15);
                hbuf[cur ^ 1][j >> 5][(((j & 31) >> 3) << 4) + b][j & 7] = (_Float16)hh;
            }
        }
        __syncthreads();
        cur ^= 1;
    }

#pragma unroll
    for (int jt = 0; jt < 2; jt++)
#pragma unroll
        for (int r = 0; r < 4; r++) {
            int b = 4 * (l >> 4) + r;
            int j = w * 32 + jt * 16 + (l & 15);
            pooled[(size_t)(bg * 16 + b) * HH + j] = pa[jt][r] / (float)len_[r];
        }
}

// ============ head: unchanged ============
__global__ __launch_bounds__(256) void head_kernel(
    const float* __restrict__ pooled, const float* __restrict__ Wp1,
    const float* __restrict__ bp1, const float* __restrict__ Wp2,
    const float* __restrict__ bp2, float* __restrict__ y0ws)
{
    __shared__ __align__(16) float psh[HH];
    __shared__ __align__(16) float rsh[HH];
    int tid = threadIdx.x, b = blockIdx.x;
    psh[tid] = pooled[(size_t)b * HH + tid];
    __syncthreads();
    float a = bp1[tid];
    const float* wr = Wp1 + (size_t)tid * HH;
#pragma unroll 8
    for (int k = 0; k < HH; k += 4) {
        float4 w = *(const float4*)(wr + k);
        a += psh[k] * w.x + psh[k + 1] * w.y + psh[k + 2] * w.z + psh[k + 3] * w.w;
    }
    rsh[tid] = fmaxf(a, 0.f);
    __syncthreads();
    if (tid < DD) {
        float acc = bp2[tid];
        const float* w2 = Wp2 + (size_t)tid * HH;
#pragma unroll 8
        for (int h = 0; h < HH; h += 4) {
            float4 w = *(const float4*)(w2 + h);
            acc += rsh[h] * w.x + rsh[h + 1] * w.y + rsh[h + 2] * w.z + rsh[h + 3] * w.w;
        }
        y0ws[(size_t)b * DD + tid] = acc;
    }
}

// ============ ODE v7: v6 math, 4 independent 16-batch groups per 1024-thr block ============
// 8 blocks x 16 waves (4 waves/SIMD). Each 256-thread group runs the validated v6 pipeline on
// its own LDS arrays; block barrier couples groups but work is identical-length, and 4x wave
// occupancy hides the per-eval LDS/barrier/MFMA latency that 1 wave/SIMD (v6) left exposed.
__global__ __launch_bounds__(1024, 4) void ode_kernel(
    const float* __restrict__ y0ws, const h8* __restrict__ A1f,
    const float* __restrict__ bd1, const h8* __restrict__ A2f,
    const float* __restrict__ bd2, const float* __restrict__ ltime,
    const float* __restrict__ lfeat, const float* __restrict__ lmask,
    float* __restrict__ pred, float* __restrict__ losso)
{
    __shared__ __align__(16) _Float16 hX[4][16 * 264];   // per-group, stride 264 (bank-balanced)
    __shared__ __align__(16) _Float16 kX[4][16 * 80];    // per-group, stride 80
    int tid = threadIdx.x;
    int grp = tid >> 8;
    int t256 = tid & 255;
    int wv = t256 >> 6, l = t256 & 63;
    int q = l >> 4, bb = l & 15;
    int b = (blockIdx.x * 4 + grp) * 16 + bb;
    _Float16* hXg = hX[grp];
    _Float16* kXg = kX[grp];

    h8 A1[4][2];
#pragma unroll
    for (int tt = 0; tt < 4; tt++)
#pragma unroll
        for (int ks = 0; ks < 2; ks++)
            A1[tt][ks] = A1f[((4 * wv + tt) * 2 + ks) * 64 + l];
    h8 A2[8];
#pragma unroll
    for (int ks = 0; ks < 8; ks++) A2[ks] = A2f[(wv * 8 + ks) * 64 + l];

    f32x4 BD1[4];
#pragma unroll
    for (int tt = 0; tt < 4; tt++)
#pragma unroll
        for (int r = 0; r < 4; r++) BD1[tt][r] = bd1[16 * (4 * wv + tt) + 4 * q + r];
    f32x4 BD2;
#pragma unroll
    for (int r = 0; r < 4; r++) BD2[r] = bd2[16 * wv + 4 * q + r];

    float y[16], kp[16], ksum[16];
#pragma unroll
    for (int ks2 = 0; ks2 < 2; ks2++)
#pragma unroll
        for (int e = 0; e < 8; e++) {
            y[ks2 * 8 + e] = y0ws[(size_t)b * DD + 32 * ks2 + 8 * q + e];
            kp[ks2 * 8 + e] = 0.f;
        }

    if (wv == 0) {   // pred/loss at ti=0
#pragma unroll
        for (int ks2 = 0; ks2 < 2; ks2++) {
            size_t idx = ((size_t)b * TT + 0) * DD + 32 * ks2 + 8 * q;
#pragma unroll
            for (int h4i = 0; h4i < 2; h4i++) {
                float4 p;
                p.x = y[ks2 * 8 + 4 * h4i + 0]; p.y = y[ks2 * 8 + 4 * h4i + 1];
                p.z = y[ks2 * 8 + 4 * h4i + 2]; p.w = y[ks2 * 8 + 4 * h4i + 3];
                *(float4*)&pred[idx + 4 * h4i] = p;
                float4 lf = *(const float4*)&lfeat[idx + 4 * h4i];
                float4 lm = *(const float4*)&lmask[idx + 4 * h4i];
                float4 lo;
                lo.x = (p.x - lf.x) * (p.x - lf.x) * (1.f - lm.x);
                lo.y = (p.y - lf.y) * (p.y - lf.y) * (1.f - lm.y);
                lo.z = (p.z - lf.z) * (p.z - lf.z) * (1.f - lm.z);
                lo.w = (p.w - lf.w) * (p.w - lf.w) * (1.f - lm.w);
                *(float4*)&losso[idx + 4 * h4i] = lo;
            }
        }
    }

    for (int iv = 0; iv < TT - 1; iv++) {
        float t0 = ltime[(size_t)b * TT + iv], t1 = ltime[(size_t)b * TT + iv + 1];
        float dt = (t1 - t0) * 0.125f;
        for (int ss = 0; ss < 8; ss++) {
#pragma unroll
            for (int i = 0; i < 16; i++) ksum[i] = 0.f;
            const float AE[4] = {0.f, 0.5f, 0.5f, 1.f};
            const float WE[4] = {1.f, 2.f, 2.f, 1.f};
#pragma unroll
            for (int e = 0; e < 4; e++) {
                float adt = AE[e] * dt;
                h8 B1[2];
#pragma unroll
                for (int ks2 = 0; ks2 < 2; ks2++) {
                    uint4 u;
                    u.x = pkrtz(y[ks2 * 8 + 0] + adt * kp[ks2 * 8 + 0], y[ks2 * 8 + 1] + adt * kp[ks2 * 8 + 1]);
                    u.y = pkrtz(y[ks2 * 8 + 2] + adt * kp[ks2 * 8 + 2], y[ks2 * 8 + 3] + adt * kp[ks2 * 8 + 3]);
                    u.z = pkrtz(y[ks2 * 8 + 4] + adt * kp[ks2 * 8 + 4], y[ks2 * 8 + 5] + adt * kp[ks2 * 8 + 5]);
                    u.w = pkrtz(y[ks2 * 8 + 6] + adt * kp[ks2 * 8 + 6], y[ks2 * 8 + 7] + adt * kp[ks2 * 8 + 7]);
                    B1[ks2] = __builtin_bit_cast(h8, u);
                }
                f32x4 C1[4];
#pragma unroll
                for (int tt = 0; tt < 4; tt++) C1[tt] = BD1[tt];
#pragma unroll
                for (int ks2 = 0; ks2 < 2; ks2++)
#pragma unroll
                    for (int tt = 0; tt < 4; tt++)
                        C1[tt] = __builtin_amdgcn_mfma_f32_16x16x32_f16(A1[tt][ks2], B1[ks2], C1[tt], 0, 0, 0);
#pragma unroll
                for (int tt = 0; tt < 4; tt++) {
                    u32 p0 = pkrtz(fmaxf(C1[tt][0], 0.f), fmaxf(C1[tt][1], 0.f));
                    u32 p1 = pkrtz(fmaxf(C1[tt][2], 0.f), fmaxf(C1[tt][3], 0.f));
                    *(uint2*)&hXg[bb * 264 + 16 * (4 * wv + tt) + 4 * q] = make_uint2(p0, p1);
                }
                __syncthreads();
                f32x4 Ca = BD2, Cb = (f32x4){0.f, 0.f, 0.f, 0.f};
#pragma unroll
                for (int ksi = 0; ksi < 8; ksi += 2) {
                    h8 B2a = *(const h8*)&hXg[bb * 264 + 32 * ksi + 8 * q];
                    h8 B2b = *(const h8*)&hXg[bb * 264 + 32 * (ksi + 1) + 8 * q];
                    Ca = __builtin_amdgcn_mfma_f32_16x16x32_f16(A2[ksi], B2a, Ca, 0, 0, 0);
                    Cb = __builtin_amdgcn_mfma_f32_16x16x32_f16(A2[ksi + 1], B2b, Cb, 0, 0, 0);
                }
                {
                    u32 p0 = pkrtz(Ca[0] + Cb[0], Ca[1] + Cb[1]);
                    u32 p1 = pkrtz(Ca[2] + Cb[2], Ca[3] + Cb[3]);
                    *(uint2*)&kXg[bb * 80 + 16 * wv + 4 * q] = make_uint2(p0, p1);
                }
                __syncthreads();
#pragma unroll
                for (int ks2 = 0; ks2 < 2; ks2++) {
                    h8 kf = *(const h8*)&kXg[bb * 80 + 32 * ks2 + 8 * q];
#pragma unroll
                    for (int e2 = 0; e2 < 8; e2++) {
                        float kv = (float)kf[e2];
                        kp[ks2 * 8 + e2] = kv;
                        ksum[ks2 * 8 + e2] += WE[e] * kv;
                    }
                }
            }
#pragma unroll
            for (int i = 0; i < 16; i++) y[i] += dt * (1.f / 6.f) * ksum[i];
        }
        if (wv == 0) {   // pred/loss at ti=iv+1
#pragma unroll
            for (int ks2 = 0; ks2 < 2; ks2++) {
                size_t idx = ((size_t)b * TT + iv + 1) * DD + 32 * ks2 + 8 * q;
#pragma unroll
                for (int h4i = 0; h4i < 2; h4i++) {
                    float4 p;
                    p.x = y[ks2 * 8 + 4 * h4i + 0]; p.y = y[ks2 * 8 + 4 * h4i + 1];
                    p.z = y[ks2 * 8 + 4 * h4i + 2]; p.w = y[ks2 * 8 + 4 * h4i + 3];
                    *(float4*)&pred[idx + 4 * h4i] = p;
                    float4 lf = *(const float4*)&lfeat[idx + 4 * h4i];
                    float4 lm = *(const float4*)&lmask[idx + 4 * h4i];
                    float4 lo;
                    lo.x = (p.x - lf.x) * (p.x - lf.x) * (1.f - lm.x);
                    lo.y = (p.y - lf.y) * (p.y - lf.y) * (1.f - lm.y);
                    lo.z = (p.z - lf.z) * (p.z - lf.z) * (1.f - lm.z);
                    lo.w = (p.w - lf.w) * (p.w - lf.w) * (1.f - lm.w);
                    *(float4*)&losso[idx + 4 * h4i] = lo;
                }
            }
        }
    }
}

extern "C" void kernel_launch(void* const* d_in, const int* in_sizes, int n_in,
                              void* d_out, int out_size, void* d_ws, size_t ws_size,
                              hipStream_t stream)
{
    const float* x      = (const float*)d_in[0];
    const int* lengths  = (const int*)d_in[1];
    const float* lfeat  = (const float*)d_in[2];
    const float* ltime  = (const float*)d_in[3];
    const float* lmask  = (const float*)d_in[4];
    const float* W_ih   = (const float*)d_in[5];
    const float* W_hh   = (const float*)d_in[6];
    const float* b_ih   = (const float*)d_in[7];
    const float* b_hh   = (const float*)d_in[8];
    const float* Wp1    = (const float*)d_in[9];
    const float* bp1    = (const float*)d_in[10];
    const float* Wp2    = (const float*)d_in[11];
    const float* bp2    = (const float*)d_in[12];
    const float* Wd1    = (const float*)d_in[13];
    const float* bd1    = (const float*)d_in[14];
    const float* Wd2    = (const float*)d_in[15];
    const float* bd2    = (const float*)d_in[16];

    float* pred  = (float*)d_out;
    float* losso = pred + (size_t)BB * TT * DD;

    char* ws = (char*)d_ws;
    h4*       xwf    = (h4*)(ws + 0);                  // 268435456
    h4*       BhhV   = (h4*)(ws + 268435456);          //    262144
    h4*       BhhL   = (h4*)(ws + 268697600);          //    131072
    h4*       BhhS   = (h4*)(ws + 268828672);          //    131072
    _Float16* Bih    = (_Float16*)(ws + 268959744);    //    327680
    float*    pooled = (float*)(ws + 269287424);       //    524288
    float*    y0ws   = (float*)(ws + 269811712);       //    131072
    h4*       A1f    = (h4*)(ws + 269942784);          //     32768
    h4*       A2f    = (h4*)(ws + 269975552);          //     32768

    prep_kernel<<<448, 256, 0, stream>>>(W_hh, W_ih, Wd1, Wd2, BhhV, BhhL, BhhS, Bih, A1f, A2f);
    xw_kernel<<<2048, 256, 0, stream>>>(x, Bih, b_ih, b_hh, xwf);
    lstm_kernel<<<32, 512, 0, stream>>>((const h8*)BhhV, (const h8*)BhhL, (const h8*)BhhS,
                                        xwf, lengths, pooled);
    head_kernel<<<BB, 256, 0, stream>>>(pooled, Wp1, bp1, Wp2, bp2, y0ws);
    ode_kernel<<<8, 1024, 0, stream>>>(y0ws, (const h8*)A1f, bd1, (const h8*)A2f, bd2,
                                       ltime, lfeat, lmask, pred, losso);
}

// Round 12
// 2600.452 us; speedup vs baseline: 3.6039x; 3.6039x over previous
//
#include <hip/hip_runtime.h>
#include <hip/hip_bf16.h>

#define BB 512
#define SS 256
#define HH 256
#define DD 64
#define TT 50
#define GG 1024   // 4*H
#define INW 129

typedef _Float16 h4 __attribute__((ext_vector_type(4)));
typedef _Float16 h8 __attribute__((ext_vector_type(8)));
typedef __fp16 hf2 __attribute__((ext_vector_type(2)));   // builtin-facing f16 pair
typedef float f32x4 __attribute__((ext_vector_type(4)));
typedef unsigned int u32;

__device__ inline float sigf(float x) { return 1.f / (1.f + __expf(-x)); }
__device__ inline float tanhf_(float x) { return 1.f - 2.f / (__expf(2.f * x) + 1.f); }

__device__ inline u32 pkrtz(float a, float b) {
    hf2 h = __builtin_amdgcn_cvt_pkrtz(a, b);
    return __builtin_bit_cast(u32, h);
}

// ============ prep: r5/r6 validated — Bhh split 4(AGPR)/2(LDS)/2(stream) ============
__global__ __launch_bounds__(256) void prep_kernel(
    const float* __restrict__ W_hh, const float* __restrict__ W_ih,
    const float* __restrict__ Wd1, const float* __restrict__ Wd2,
    h4* __restrict__ BhhV4, h4* __restrict__ BhhL4, h4* __restrict__ BhhS4,
    _Float16* __restrict__ Bih, h4* __restrict__ A1f4, h4* __restrict__ A2f4)
{
    int idx = blockIdx.x * 256 + threadIdx.x;
    if (idx < 65536) {
        int eh = idx & 1;
        int l = (idx >> 1) & 63;
        int ks = (idx >> 7) & 7;
        int s = (idx >> 10) & 7;
        int w = (idx >> 13) & 7;
        int g = s & 3, jt = s >> 2;
        int n = g * 256 + w * 32 + jt * 16 + (l & 15);
        int k = 32 * ks + 8 * (l >> 4) + 4 * eh;
        float4 v = *(const float4*)(W_hh + (size_t)n * HH + k);
        h4 o; o[0] = (_Float16)v.x; o[1] = (_Float16)v.y; o[2] = (_Float16)v.z; o[3] = (_Float16)v.w;
        if (ks < 4)      BhhV4[(((w * 8 + s) * 4 + ks) * 64 + l) * 2 + eh] = o;
        else if (ks < 6) BhhL4[(((w * 8 + s) * 2 + (ks - 4)) * 64 + l) * 2 + eh] = o;
        else             BhhS4[(((w * 8 + s) * 2 + (ks - 6)) * 64 + l) * 2 + eh] = o;
    } else if (idx < 106496) {
        int fj = idx - 65536;
        int eh = fj & 1;
        int l = (fj >> 1) & 63;
        int si = fj >> 7;              // [0,320) = ntile*5 + ks
        int ks = si % 5;
        int ntile = si / 5;
        int n = ntile * 16 + (l & 15);
        int k = 32 * ks + 8 * (l >> 4) + 4 * eh;
        h4 o;
#pragma unroll
        for (int i = 0; i < 4; i++) {
            int kk = k + i;
            o[i] = (_Float16)((kk < INW) ? W_ih[(size_t)n * INW + kk] : 0.f);
        }
        *(h4*)(Bih + (size_t)fj * 4) = o;
    } else if (idx < 110592) {
        int fj = idx - 106496;         // A1f
        int eh = fj & 1;
        int l = (fj >> 1) & 63;
        int slot = fj >> 7;            // t*2+ks
        int ks = slot & 1, t = slot >> 1;
        int row = 16 * t + (l & 15);
        int k = 32 * ks + 8 * (l >> 4) + 4 * eh;
        h4 o;
#pragma unroll
        for (int i = 0; i < 4; i++) o[i] = (_Float16)Wd1[(size_t)row * DD + k + i];
        A1f4[fj] = o;
    } else if (idx < 114688) {
        int fj = idx - 110592;         // A2f
        int eh = fj & 1;
        int l = (fj >> 1) & 63;
        int slot = fj >> 7;            // t2*8+ks
        int ks = slot & 7, t2 = slot >> 3;
        int row = 16 * t2 + (l & 15);
        int k = 32 * ks + 8 * (l >> 4) + 4 * eh;
        h4 o;
#pragma unroll
        for (int i = 0; i < 4; i++) o[i] = (_Float16)Wd2[(size_t)row * HH + k + i];
        A2f4[fj] = o;
    }
}

// ============ xw GEMM (MFMA): validated r5 version (8-wave slot mapping) ============
__global__ __launch_bounds__(256) void xw_kernel(
    const float* __restrict__ x, const _Float16* __restrict__ Bih,
    const float* __restrict__ b_ih, const float* __restrict__ b_hh,
    h4* __restrict__ xwf)
{
    __shared__ __align__(16) _Float16 ash[4][5][64][8];   // 20 KB, A-frag layout
    int tid = threadIdx.x;
    int w4 = tid >> 6, l = tid & 63;
    int bx = blockIdx.x;
    int t = bx >> 3, Bb = bx & 7;           // 64 batch-rows: b = Bb*64 + rr

    for (int i = tid; i < 64 * 160; i += 256) {
        int rr = i / 160, kk = i % 160;
        float v = (kk < INW) ? x[((size_t)(Bb * 64 + rr) * SS + t) * INW + kk] : 0.f;
        ash[rr >> 4][kk >> 5][(((kk & 31) >> 3) << 4) + (rr & 15)][kk & 7] = (_Float16)v;
    }
    __syncthreads();

    h8 A[4][5];
#pragma unroll
    for (int ms = 0; ms < 4; ms++)
#pragma unroll
        for (int ks = 0; ks < 5; ks++)
            A[ms][ks] = *(h8*)&ash[ms][ks][l][0];

    const h8* Bih8 = (const h8*)Bih;
    for (int nt16 = 0; nt16 < 16; nt16++) {
        int ntile = w4 * 16 + nt16;
        h8 Bv[5];
#pragma unroll
        for (int ks = 0; ks < 5; ks++) Bv[ks] = Bih8[(ntile * 5 + ks) * 64 + l];
        int nb = ntile * 16 + (l & 15);
        float bias = b_ih[nb] + b_hh[nb];
        f32x4 acc[4];
#pragma unroll
        for (int ms = 0; ms < 4; ms++) acc[ms] = (f32x4){0.f, 0.f, 0.f, 0.f};
#pragma unroll
        for (int ks = 0; ks < 5; ks++)
#pragma unroll
            for (int ms = 0; ms < 4; ms++)
                acc[ms] = __builtin_amdgcn_mfma_f32_16x16x32_f16(A[ms][ks], Bv[ks], acc[ms], 0, 0, 0);
        // slot for 8-wave LSTM: w = (ntile&15)>>1, jt = ntile&1, g = ntile>>4
        int slot = ((ntile & 15) >> 1) * 8 + (ntile & 1) * 4 + (ntile >> 4);
#pragma unroll
        for (int ms = 0; ms < 4; ms++) {
            int bg = Bb * 4 + ms;
            h4 o;
#pragma unroll
            for (int r = 0; r < 4; r++) o[r] = (_Float16)(acc[ms][r] + bias);
            xwf[(((size_t)bg * SS + t) * 64 + slot) * 64 + l] = o;
        }
    }
}

// ============ LSTM: exact round-5 kernel (measured 1108 us; register-feasible config) ============
__global__ __launch_bounds__(512, 2) void lstm_kernel(
    const h8* __restrict__ BhhV, const h8* __restrict__ BhhL, const h8* __restrict__ BhhS,
    const h4* __restrict__ xwf, const int* __restrict__ lengths, float* __restrict__ pooled)
{
    __shared__ __align__(16) _Float16 Wlds[65536];        // 128 KB: ks4-5 weight fragments
    __shared__ __align__(16) _Float16 hbuf[2][8][64][8];  // 16 KB double-buffered A-frag h
    int tid = threadIdx.x;
    int w = tid >> 6, l = tid & 63;
    int bg = blockIdx.x;

    {   // copy ks4-5 weights into LDS (linear, 128 KB)
        const uint4* src = (const uint4*)BhhL;
        uint4* dst = (uint4*)Wlds;
#pragma unroll
        for (int i = 0; i < 16; i++) dst[i * 512 + tid] = src[i * 512 + tid];
    }

    h8 Wv[8][4];
#pragma unroll
    for (int s = 0; s < 8; s++)
#pragma unroll
        for (int ks = 0; ks < 4; ks++)
            Wv[s][ks] = BhhV[((w * 8 + s) * 4 + ks) * 64 + l];

    int len_[4];
    float c_[2][4], pa[2][4];
#pragma unroll
    for (int r = 0; r < 4; r++) {
        int b = 4 * (l >> 4) + r;
        len_[r] = lengths[bg * 16 + b];
#pragma unroll
        for (int jt = 0; jt < 2; jt++) { c_[jt][r] = 0.f; pa[jt][r] = 0.f; }
    }

    {   // zero h buffers (h0 = 0): 1024 uint4, 2 per thread
        uint4* hz = (uint4*)hbuf;
        hz[tid] = make_uint4(0, 0, 0, 0);
        hz[512 + tid] = make_uint4(0, 0, 0, 0);
    }
    __syncthreads();

    int cur = 0;
    for (int t = 0; t < SS; t++) {
        const h4* xpb = xwf + (((size_t)bg * SS + t) * 64 + w * 8) * 64 + l;
        int zoff = 0;
        asm volatile("" : "+v"(zoff));            // block LICM: force per-step re-load of streamed weights
        const h8* bS = BhhS + zoff;
#pragma unroll
        for (int jt = 0; jt < 2; jt++) {
            h4 xv[4];
#pragma unroll
            for (int g = 0; g < 4; g++) xv[g] = xpb[(jt * 4 + g) * 64];
            h8 Ws[4];
#pragma unroll
            for (int g = 0; g < 4; g++) Ws[g] = bS[((w * 8 + jt * 4 + g) * 2 + 0) * 64 + l];
            f32x4 acc[4];
#pragma unroll
            for (int g = 0; g < 4; g++) acc[g] = (f32x4){0.f, 0.f, 0.f, 0.f};
            // ks 0-3 from VGPR/AGPR weights
#pragma unroll
            for (int ks = 0; ks < 4; ks++) {
                h8 A = *(const h8*)&hbuf[cur][ks][l][0];
#pragma unroll
                for (int g = 0; g < 4; g++)
                    acc[g] = __builtin_amdgcn_mfma_f32_16x16x32_f16(A, Wv[jt * 4 + g][ks], acc[g], 0, 0, 0);
            }
            // ks 6 (streamed, landed)
            {
                h8 A = *(const h8*)&hbuf[cur][6][l][0];
#pragma unroll
                for (int g = 0; g < 4; g++)
                    acc[g] = __builtin_amdgcn_mfma_f32_16x16x32_f16(A, Ws[g], acc[g], 0, 0, 0);
            }
            // reissue stream for ks 7 into same regs
#pragma unroll
            for (int g = 0; g < 4; g++) Ws[g] = bS[((w * 8 + jt * 4 + g) * 2 + 1) * 64 + l];
            // ks 4-5 from LDS
#pragma unroll
            for (int ks = 4; ks < 6; ks++) {
                h8 A = *(const h8*)&hbuf[cur][ks][l][0];
#pragma unroll
                for (int g = 0; g < 4; g++) {
                    h8 Bw = *(const h8*)&Wlds[(((w * 8 + jt * 4 + g) * 2 + (ks - 4)) * 64 + l) * 8];
                    acc[g] = __builtin_amdgcn_mfma_f32_16x16x32_f16(A, Bw, acc[g], 0, 0, 0);
                }
            }
            // ks 7
            {
                h8 A = *(const h8*)&hbuf[cur][7][l][0];
#pragma unroll
                for (int g = 0; g < 4; g++)
                    acc[g] = __builtin_amdgcn_mfma_f32_16x16x32_f16(A, Ws[g], acc[g], 0, 0, 0);
            }
            // gates + h update
#pragma unroll
            for (int r = 0; r < 4; r++) {
                float gi = acc[0][r] + (float)xv[0][r];
                float gf = acc[1][r] + (float)xv[1][r];
                float gg = acc[2][r] + (float)xv[2][r];
                float go = acc[3][r] + (float)xv[3][r];
                float cc = sigf(gf) * c_[jt][r] + sigf(gi) * tanhf_(gg);
                c_[jt][r] = cc;
                float hh = sigf(go) * tanhf_(cc);
                if (t < len_[r]) pa[jt][r] += hh;
                int b = 4 * (l >> 4) + r;
                int j = w * 32 + jt * 16 + (l & 15);
                hbuf[cur ^ 1][j >> 5][(((j & 31) >> 3) << 4) + b][j & 7] = (_Float16)hh;
            }
        }
        __syncthreads();
        cur ^= 1;
    }

#pragma unroll
    for (int jt = 0; jt < 2; jt++)
#pragma unroll
        for (int r = 0; r < 4; r++) {
            int b = 4 * (l >> 4) + r;
            int j = w * 32 + jt * 16 + (l & 15);
            pooled[(size_t)(bg * 16 + b) * HH + j] = pa[jt][r] / (float)len_[r];
        }
}

// ============ head: unchanged ============
__global__ __launch_bounds__(256) void head_kernel(
    const float* __restrict__ pooled, const float* __restrict__ Wp1,
    const float* __restrict__ bp1, const float* __restrict__ Wp2,
    const float* __restrict__ bp2, float* __restrict__ y0ws)
{
    __shared__ __align__(16) float psh[HH];
    __shared__ __align__(16) float rsh[HH];
    int tid = threadIdx.x, b = blockIdx.x;
    psh[tid] = pooled[(size_t)b * HH + tid];
    __syncthreads();
    float a = bp1[tid];
    const float* wr = Wp1 + (size_t)tid * HH;
#pragma unroll 8
    for (int k = 0; k < HH; k += 4) {
        float4 w = *(const float4*)(wr + k);
        a += psh[k] * w.x + psh[k + 1] * w.y + psh[k + 2] * w.z + psh[k + 3] * w.w;
    }
    rsh[tid] = fmaxf(a, 0.f);
    __syncthreads();
    if (tid < DD) {
        float acc = bp2[tid];
        const float* w2 = Wp2 + (size_t)tid * HH;
#pragma unroll 8
        for (int h = 0; h < HH; h += 4) {
            float4 w = *(const float4*)(w2 + h);
            acc += rsh[h] * w.x + rsh[h + 1] * w.y + rsh[h + 2] * w.z + rsh[h + 3] * w.w;
        }
        y0ws[(size_t)b * DD + tid] = acc;
    }
}

// ============ ODE v8: v6 math, 2 groups per 512-thr block, __launch_bounds__(512,2) ============
// The ONLY proven multi-wave-per-SIMD register regime (r5 LSTM: 256-reg budget, no spill).
// 16 blocks x 8 waves = 2 waves/SIMD; each 256-thr group runs the validated v6 pipeline on its
// own LDS arrays. r3/r9/r11 showed (1024,4) collapses the allocator -> never again.
__global__ __launch_bounds__(512, 2) void ode_kernel(
    const float* __restrict__ y0ws, const h8* __restrict__ A1f,
    const float* __restrict__ bd1, const h8* __restrict__ A2f,
    const float* __restrict__ bd2, const float* __restrict__ ltime,
    const float* __restrict__ lfeat, const float* __restrict__ lmask,
    float* __restrict__ pred, float* __restrict__ losso)
{
    __shared__ __align__(16) _Float16 hX[2][16 * 264];   // per-group, stride 264 (bank-balanced)
    __shared__ __align__(16) _Float16 kX[2][16 * 80];    // per-group, stride 80
    int tid = threadIdx.x;
    int grp = tid >> 8;
    int t256 = tid & 255;
    int wv = t256 >> 6, l = t256 & 63;
    int q = l >> 4, bb = l & 15;
    int b = (blockIdx.x * 2 + grp) * 16 + bb;
    _Float16* hXg = hX[grp];
    _Float16* kXg = kX[grp];

    h8 A1[4][2];
#pragma unroll
    for (int tt = 0; tt < 4; tt++)
#pragma unroll
        for (int ks = 0; ks < 2; ks++)
            A1[tt][ks] = A1f[((4 * wv + tt) * 2 + ks) * 64 + l];
    h8 A2[8];
#pragma unroll
    for (int ks = 0; ks < 8; ks++) A2[ks] = A2f[(wv * 8 + ks) * 64 + l];

    f32x4 BD1[4];
#pragma unroll
    for (int tt = 0; tt < 4; tt++)
#pragma unroll
        for (int r = 0; r < 4; r++) BD1[tt][r] = bd1[16 * (4 * wv + tt) + 4 * q + r];
    f32x4 BD2;
#pragma unroll
    for (int r = 0; r < 4; r++) BD2[r] = bd2[16 * wv + 4 * q + r];

    float y[16], kp[16], ksum[16];
#pragma unroll
    for (int ks2 = 0; ks2 < 2; ks2++)
#pragma unroll
        for (int e = 0; e < 8; e++) {
            y[ks2 * 8 + e] = y0ws[(size_t)b * DD + 32 * ks2 + 8 * q + e];
            kp[ks2 * 8 + e] = 0.f;
        }

    if (wv == 0) {   // pred/loss at ti=0
#pragma unroll
        for (int ks2 = 0; ks2 < 2; ks2++) {
            size_t idx = ((size_t)b * TT + 0) * DD + 32 * ks2 + 8 * q;
#pragma unroll
            for (int h4i = 0; h4i < 2; h4i++) {
                float4 p;
                p.x = y[ks2 * 8 + 4 * h4i + 0]; p.y = y[ks2 * 8 + 4 * h4i + 1];
                p.z = y[ks2 * 8 + 4 * h4i + 2]; p.w = y[ks2 * 8 + 4 * h4i + 3];
                *(float4*)&pred[idx + 4 * h4i] = p;
                float4 lf = *(const float4*)&lfeat[idx + 4 * h4i];
                float4 lm = *(const float4*)&lmask[idx + 4 * h4i];
                float4 lo;
                lo.x = (p.x - lf.x) * (p.x - lf.x) * (1.f - lm.x);
                lo.y = (p.y - lf.y) * (p.y - lf.y) * (1.f - lm.y);
                lo.z = (p.z - lf.z) * (p.z - lf.z) * (1.f - lm.z);
                lo.w = (p.w - lf.w) * (p.w - lf.w) * (1.f - lm.w);
                *(float4*)&losso[idx + 4 * h4i] = lo;
            }
        }
    }

    for (int iv = 0; iv < TT - 1; iv++) {
        float t0 = ltime[(size_t)b * TT + iv], t1 = ltime[(size_t)b * TT + iv + 1];
        float dt = (t1 - t0) * 0.125f;
        for (int ss = 0; ss < 8; ss++) {
#pragma unroll
            for (int i = 0; i < 16; i++) ksum[i] = 0.f;
            const float AE[4] = {0.f, 0.5f, 0.5f, 1.f};
            const float WE[4] = {1.f, 2.f, 2.f, 1.f};
#pragma unroll
            for (int e = 0; e < 4; e++) {
                float adt = AE[e] * dt;
                h8 B1[2];
#pragma unroll
                for (int ks2 = 0; ks2 < 2; ks2++) {
                    uint4 u;
                    u.x = pkrtz(y[ks2 * 8 + 0] + adt * kp[ks2 * 8 + 0], y[ks2 * 8 + 1] + adt * kp[ks2 * 8 + 1]);
                    u.y = pkrtz(y[ks2 * 8 + 2] + adt * kp[ks2 * 8 + 2], y[ks2 * 8 + 3] + adt * kp[ks2 * 8 + 3]);
                    u.z = pkrtz(y[ks2 * 8 + 4] + adt * kp[ks2 * 8 + 4], y[ks2 * 8 + 5] + adt * kp[ks2 * 8 + 5]);
                    u.w = pkrtz(y[ks2 * 8 + 6] + adt * kp[ks2 * 8 + 6], y[ks2 * 8 + 7] + adt * kp[ks2 * 8 + 7]);
                    B1[ks2] = __builtin_bit_cast(h8, u);
                }
                f32x4 C1[4];
#pragma unroll
                for (int tt = 0; tt < 4; tt++) C1[tt] = BD1[tt];
#pragma unroll
                for (int ks2 = 0; ks2 < 2; ks2++)
#pragma unroll
                    for (int tt = 0; tt < 4; tt++)
                        C1[tt] = __builtin_amdgcn_mfma_f32_16x16x32_f16(A1[tt][ks2], B1[ks2], C1[tt], 0, 0, 0);
#pragma unroll
                for (int tt = 0; tt < 4; tt++) {
                    u32 p0 = pkrtz(fmaxf(C1[tt][0], 0.f), fmaxf(C1[tt][1], 0.f));
                    u32 p1 = pkrtz(fmaxf(C1[tt][2], 0.f), fmaxf(C1[tt][3], 0.f));
                    *(uint2*)&hXg[bb * 264 + 16 * (4 * wv + tt) + 4 * q] = make_uint2(p0, p1);
                }
                __syncthreads();
                f32x4 Ca = BD2, Cb = (f32x4){0.f, 0.f, 0.f, 0.f};
#pragma unroll
                for (int ksi = 0; ksi < 8; ksi += 2) {
                    h8 B2a = *(const h8*)&hXg[bb * 264 + 32 * ksi + 8 * q];
                    h8 B2b = *(const h8*)&hXg[bb * 264 + 32 * (ksi + 1) + 8 * q];
                    Ca = __builtin_amdgcn_mfma_f32_16x16x32_f16(A2[ksi], B2a, Ca, 0, 0, 0);
                    Cb = __builtin_amdgcn_mfma_f32_16x16x32_f16(A2[ksi + 1], B2b, Cb, 0, 0, 0);
                }
                {
                    u32 p0 = pkrtz(Ca[0] + Cb[0], Ca[1] + Cb[1]);
                    u32 p1 = pkrtz(Ca[2] + Cb[2], Ca[3] + Cb[3]);
                    *(uint2*)&kXg[bb * 80 + 16 * wv + 4 * q] = make_uint2(p0, p1);
                }
                __syncthreads();
#pragma unroll
                for (int ks2 = 0; ks2 < 2; ks2++) {
                    h8 kf = *(const h8*)&kXg[bb * 80 + 32 * ks2 + 8 * q];
#pragma unroll
                    for (int e2 = 0; e2 < 8; e2++) {
                        float kv = (float)kf[e2];
                        kp[ks2 * 8 + e2] = kv;
                        ksum[ks2 * 8 + e2] += WE[e] * kv;
                    }
                }
            }
#pragma unroll
            for (int i = 0; i < 16; i++) y[i] += dt * (1.f / 6.f) * ksum[i];
        }
        if (wv == 0) {   // pred/loss at ti=iv+1
#pragma unroll
            for (int ks2 = 0; ks2 < 2; ks2++) {
                size_t idx = ((size_t)b * TT + iv + 1) * DD + 32 * ks2 + 8 * q;
#pragma unroll
                for (int h4i = 0; h4i < 2; h4i++) {
                    float4 p;
                    p.x = y[ks2 * 8 + 4 * h4i + 0]; p.y = y[ks2 * 8 + 4 * h4i + 1];
                    p.z = y[ks2 * 8 + 4 * h4i + 2]; p.w = y[ks2 * 8 + 4 * h4i + 3];
                    *(float4*)&pred[idx + 4 * h4i] = p;
                    float4 lf = *(const float4*)&lfeat[idx + 4 * h4i];
                    float4 lm = *(const float4*)&lmask[idx + 4 * h4i];
                    float4 lo;
                    lo.x = (p.x - lf.x) * (p.x - lf.x) * (1.f - lm.x);
                    lo.y = (p.y - lf.y) * (p.y - lf.y) * (1.f - lm.y);
                    lo.z = (p.z - lf.z) * (p.z - lf.z) * (1.f - lm.z);
                    lo.w = (p.w - lf.w) * (p.w - lf.w) * (1.f - lm.w);
                    *(float4*)&losso[idx + 4 * h4i] = lo;
                }
            }
        }
    }
}

extern "C" void kernel_launch(void* const* d_in, const int* in_sizes, int n_in,
                              void* d_out, int out_size, void* d_ws, size_t ws_size,
                              hipStream_t stream)
{
    const float* x      = (const float*)d_in[0];
    const int* lengths  = (const int*)d_in[1];
    const float* lfeat  = (const float*)d_in[2];
    const float* ltime  = (const float*)d_in[3];
    const float* lmask  = (const float*)d_in[4];
    const float* W_ih   = (const float*)d_in[5];
    const float* W_hh   = (const float*)d_in[6];
    const float* b_ih   = (const float*)d_in[7];
    const float* b_hh   = (const float*)d_in[8];
    const float* Wp1    = (const float*)d_in[9];
    const float* bp1    = (const float*)d_in[10];
    const float* Wp2    = (const float*)d_in[11];
    const float* bp2    = (const float*)d_in[12];
    const float* Wd1    = (const float*)d_in[13];
    const float* bd1    = (const float*)d_in[14];
    const float* Wd2    = (const float*)d_in[15];
    const float* bd2    = (const float*)d_in[16];

    float* pred  = (float*)d_out;
    float* losso = pred + (size_t)BB * TT * DD;

    char* ws = (char*)d_ws;
    h4*       xwf    = (h4*)(ws + 0);                  // 268435456
    h4*       BhhV   = (h4*)(ws + 268435456);          //    262144
    h4*       BhhL   = (h4*)(ws + 268697600);          //    131072
    h4*       BhhS   = (h4*)(ws + 268828672);          //    131072
    _Float16* Bih    = (_Float16*)(ws + 268959744);    //    327680
    float*    pooled = (float*)(ws + 269287424);       //    524288
    float*    y0ws   = (float*)(ws + 269811712);       //    131072
    h4*       A1f    = (h4*)(ws + 269942784);          //     32768
    h4*       A2f    = (h4*)(ws + 269975552);          //     32768

    prep_kernel<<<448, 256, 0, stream>>>(W_hh, W_ih, Wd1, Wd2, BhhV, BhhL, BhhS, Bih, A1f, A2f);
    xw_kernel<<<2048, 256, 0, stream>>>(x, Bih, b_ih, b_hh, xwf);
    lstm_kernel<<<32, 512, 0, stream>>>((const h8*)BhhV, (const h8*)BhhL, (const h8*)BhhS,
                                        xwf, lengths, pooled);
    head_kernel<<<BB, 256, 0, stream>>>(pooled, Wp1, bp1, Wp2, bp2, y0ws);
    ode_kernel<<<16, 512, 0, stream>>>(y0ws, (const h8*)A1f, bd1, (const h8*)A2f, bd2,
                                       ltime, lfeat, lmask, pred, losso);
}

// Round 13
// 2353.034 us; speedup vs baseline: 3.9828x; 1.1051x over previous
//
#include <hip/hip_runtime.h>
#include <hip/hip_bf16.h>

#define BB 512
#define SS 256
#define HH 256
#define DD 64
#define TT 50
#define GG 1024   // 4*H
#define INW 129

typedef _Float16 h4 __attribute__((ext_vector_type(4)));
typedef _Float16 h8 __attribute__((ext_vector_type(8)));
typedef __fp16 hf2 __attribute__((ext_vector_type(2)));   // builtin-facing f16 pair
typedef float f32x4 __attribute__((ext_vector_type(4)));
typedef unsigned int u32;

__device__ inline float sigf(float x) { return 1.f / (1.f + __expf(-x)); }
__device__ inline float tanhf_(float x) { return 1.f - 2.f / (__expf(2.f * x) + 1.f); }

__device__ inline u32 pkrtz(float a, float b) {
    hf2 h = __builtin_amdgcn_cvt_pkrtz(a, b);
    return __builtin_bit_cast(u32, h);
}
__device__ inline float fdot2u(u32 a, u32 b, float c) {
    return __builtin_amdgcn_fdot2(__builtin_bit_cast(hf2, a), __builtin_bit_cast(hf2, b), c, false);
}

// ============ prep: r5-validated layouts ============
// Bhh split 4(AGPR)/2(LDS)/2(stream); Bih; Wd1p/Wd2p packed-f16 pairs for fdot2 ODE.
__global__ __launch_bounds__(256) void prep_kernel(
    const float* __restrict__ W_hh, const float* __restrict__ W_ih,
    const float* __restrict__ Wd1, const float* __restrict__ Wd2,
    h4* __restrict__ BhhV4, h4* __restrict__ BhhL4, h4* __restrict__ BhhS4,
    _Float16* __restrict__ Bih, u32* __restrict__ Wd1p, u32* __restrict__ Wd2p)
{
    int idx = blockIdx.x * 256 + threadIdx.x;
    if (idx < 65536) {
        int eh = idx & 1;
        int l = (idx >> 1) & 63;
        int ks = (idx >> 7) & 7;
        int s = (idx >> 10) & 7;
        int w = (idx >> 13) & 7;
        int g = s & 3, jt = s >> 2;
        int n = g * 256 + w * 32 + jt * 16 + (l & 15);
        int k = 32 * ks + 8 * (l >> 4) + 4 * eh;
        float4 v = *(const float4*)(W_hh + (size_t)n * HH + k);
        h4 o; o[0] = (_Float16)v.x; o[1] = (_Float16)v.y; o[2] = (_Float16)v.z; o[3] = (_Float16)v.w;
        if (ks < 4)      BhhV4[(((w * 8 + s) * 4 + ks) * 64 + l) * 2 + eh] = o;
        else if (ks < 6) BhhL4[(((w * 8 + s) * 2 + (ks - 4)) * 64 + l) * 2 + eh] = o;
        else             BhhS4[(((w * 8 + s) * 2 + (ks - 6)) * 64 + l) * 2 + eh] = o;
    } else if (idx < 65536 + 40960) {
        int fj = idx - 65536;
        int eh = fj & 1;
        int l = (fj >> 1) & 63;
        int si = fj >> 7;              // [0,320) = ntile*5 + ks
        int ks = si % 5;
        int ntile = si / 5;
        int n = ntile * 16 + (l & 15);
        int k = 32 * ks + 8 * (l >> 4) + 4 * eh;
        h4 o;
#pragma unroll
        for (int i = 0; i < 4; i++) {
            int kk = k + i;
            o[i] = (_Float16)((kk < INW) ? W_ih[(size_t)n * INW + kk] : 0.f);
        }
        *(h4*)(Bih + (size_t)fj * 4) = o;
    } else if (idx < 106496 + 8192) {
        int j2 = idx - 106496;
        int j = j2 >> 8, i = j2 & 255;
        Wd1p[j2] = pkrtz(Wd1[i * DD + 2 * j], Wd1[i * DD + 2 * j + 1]);
    } else if (idx < 114688 + 8192) {
        int j2 = idx - 114688;
        int j = j2 >> 8, t = j2 & 255;
        int o = ((t >> 6) << 4) + (t & 15);
        int q = (t >> 4) & 3;
        Wd2p[j2] = pkrtz(Wd2[(size_t)o * HH + q * 64 + 2 * j],
                         Wd2[(size_t)o * HH + q * 64 + 2 * j + 1]);
    }
}

// ============ xw GEMM (MFMA): validated r5 version (8-wave slot mapping) ============
__global__ __launch_bounds__(256) void xw_kernel(
    const float* __restrict__ x, const _Float16* __restrict__ Bih,
    const float* __restrict__ b_ih, const float* __restrict__ b_hh,
    h4* __restrict__ xwf)
{
    __shared__ __align__(16) _Float16 ash[4][5][64][8];   // 20 KB, A-frag layout
    int tid = threadIdx.x;
    int w4 = tid >> 6, l = tid & 63;
    int bx = blockIdx.x;
    int t = bx >> 3, Bb = bx & 7;           // 64 batch-rows: b = Bb*64 + rr

    for (int i = tid; i < 64 * 160; i += 256) {
        int rr = i / 160, kk = i % 160;
        float v = (kk < INW) ? x[((size_t)(Bb * 64 + rr) * SS + t) * INW + kk] : 0.f;
        ash[rr >> 4][kk >> 5][(((kk & 31) >> 3) << 4) + (rr & 15)][kk & 7] = (_Float16)v;
    }
    __syncthreads();

    h8 A[4][5];
#pragma unroll
    for (int ms = 0; ms < 4; ms++)
#pragma unroll
        for (int ks = 0; ks < 5; ks++)
            A[ms][ks] = *(h8*)&ash[ms][ks][l][0];

    const h8* Bih8 = (const h8*)Bih;
    for (int nt16 = 0; nt16 < 16; nt16++) {
        int ntile = w4 * 16 + nt16;
        h8 Bv[5];
#pragma unroll
        for (int ks = 0; ks < 5; ks++) Bv[ks] = Bih8[(ntile * 5 + ks) * 64 + l];
        int nb = ntile * 16 + (l & 15);
        float bias = b_ih[nb] + b_hh[nb];
        f32x4 acc[4];
#pragma unroll
        for (int ms = 0; ms < 4; ms++) acc[ms] = (f32x4){0.f, 0.f, 0.f, 0.f};
#pragma unroll
        for (int ks = 0; ks < 5; ks++)
#pragma unroll
            for (int ms = 0; ms < 4; ms++)
                acc[ms] = __builtin_amdgcn_mfma_f32_16x16x32_f16(A[ms][ks], Bv[ks], acc[ms], 0, 0, 0);
        // slot for 8-wave LSTM: w = (ntile&15)>>1, jt = ntile&1, g = ntile>>4
        int slot = ((ntile & 15) >> 1) * 8 + (ntile & 1) * 4 + (ntile >> 4);
#pragma unroll
        for (int ms = 0; ms < 4; ms++) {
            int bg = Bb * 4 + ms;
            h4 o;
#pragma unroll
            for (int r = 0; r < 4; r++) o[r] = (_Float16)(acc[ms][r] + bias);
            xwf[(((size_t)bg * SS + t) * 64 + slot) * 64 + l] = o;
        }
    }
}

// ============ LSTM: r5 kernel + xv hoist (both jt's 8 loads at step top) ============
// Single-variable change vs the measured-1108us r5: xv[8] issued before any compute, so jt1's
// gate pre-activations have ~2500 cyc of cover instead of ~300. +8 VGPR (128V+128A = cap).
// Spill tripwire: WRITE_SIZE (512 KB good, >2 MB = spilled -> revert).
__global__ __launch_bounds__(512, 2) void lstm_kernel(
    const h8* __restrict__ BhhV, const h8* __restrict__ BhhL, const h8* __restrict__ BhhS,
    const h4* __restrict__ xwf, const int* __restrict__ lengths, float* __restrict__ pooled)
{
    __shared__ __align__(16) _Float16 Wlds[65536];        // 128 KB: ks4-5 weight fragments
    __shared__ __align__(16) _Float16 hbuf[2][8][64][8];  // 16 KB double-buffered A-frag h
    int tid = threadIdx.x;
    int w = tid >> 6, l = tid & 63;
    int bg = blockIdx.x;

    {   // copy ks4-5 weights into LDS (linear, 128 KB)
        const uint4* src = (const uint4*)BhhL;
        uint4* dst = (uint4*)Wlds;
#pragma unroll
        for (int i = 0; i < 16; i++) dst[i * 512 + tid] = src[i * 512 + tid];
    }

    h8 Wv[8][4];
#pragma unroll
    for (int s = 0; s < 8; s++)
#pragma unroll
        for (int ks = 0; ks < 4; ks++)
            Wv[s][ks] = BhhV[((w * 8 + s) * 4 + ks) * 64 + l];

    int len_[4];
    float c_[2][4], pa[2][4];
#pragma unroll
    for (int r = 0; r < 4; r++) {
        int b = 4 * (l >> 4) + r;
        len_[r] = lengths[bg * 16 + b];
#pragma unroll
        for (int jt = 0; jt < 2; jt++) { c_[jt][r] = 0.f; pa[jt][r] = 0.f; }
    }

    {   // zero h buffers (h0 = 0): 1024 uint4, 2 per thread
        uint4* hz = (uint4*)hbuf;
        hz[tid] = make_uint4(0, 0, 0, 0);
        hz[512 + tid] = make_uint4(0, 0, 0, 0);
    }
    __syncthreads();

    int cur = 0;
    for (int t = 0; t < SS; t++) {
        // HOIST: issue ALL xv loads for this step (both jt) before any compute
        const h4* xpb = xwf + (((size_t)bg * SS + t) * 64 + w * 8) * 64 + l;
        h4 xv[8];
#pragma unroll
        for (int s = 0; s < 8; s++) xv[s] = xpb[s * 64];

        int zoff = 0;
        asm volatile("" : "+v"(zoff));            // block LICM: force per-step re-load of streamed weights
        const h8* bS = BhhS + zoff;
#pragma unroll
        for (int jt = 0; jt < 2; jt++) {
            h8 Ws[4];
#pragma unroll
            for (int g = 0; g < 4; g++) Ws[g] = bS[((w * 8 + jt * 4 + g) * 2 + 0) * 64 + l];
            f32x4 acc[4];
#pragma unroll
            for (int g = 0; g < 4; g++) acc[g] = (f32x4){0.f, 0.f, 0.f, 0.f};
            // ks 0-3 from VGPR/AGPR weights
#pragma unroll
            for (int ks = 0; ks < 4; ks++) {
                h8 A = *(const h8*)&hbuf[cur][ks][l][0];
#pragma unroll
                for (int g = 0; g < 4; g++)
                    acc[g] = __builtin_amdgcn_mfma_f32_16x16x32_f16(A, Wv[jt * 4 + g][ks], acc[g], 0, 0, 0);
            }
            // ks 6 (streamed, landed)
            {
                h8 A = *(const h8*)&hbuf[cur][6][l][0];
#pragma unroll
                for (int g = 0; g < 4; g++)
                    acc[g] = __builtin_amdgcn_mfma_f32_16x16x32_f16(A, Ws[g], acc[g], 0, 0, 0);
            }
            // reissue stream for ks 7 into same regs
#pragma unroll
            for (int g = 0; g < 4; g++) Ws[g] = bS[((w * 8 + jt * 4 + g) * 2 + 1) * 64 + l];
            // ks 4-5 from LDS
#pragma unroll
            for (int ks = 4; ks < 6; ks++) {
                h8 A = *(const h8*)&hbuf[cur][ks][l][0];
#pragma unroll
                for (int g = 0; g < 4; g++) {
                    h8 Bw = *(const h8*)&Wlds[(((w * 8 + jt * 4 + g) * 2 + (ks - 4)) * 64 + l) * 8];
                    acc[g] = __builtin_amdgcn_mfma_f32_16x16x32_f16(A, Bw, acc[g], 0, 0, 0);
                }
            }
            // ks 7
            {
                h8 A = *(const h8*)&hbuf[cur][7][l][0];
#pragma unroll
                for (int g = 0; g < 4; g++)
                    acc[g] = __builtin_amdgcn_mfma_f32_16x16x32_f16(A, Ws[g], acc[g], 0, 0, 0);
            }
            // gates + h update
#pragma unroll
            for (int r = 0; r < 4; r++) {
                float gi = acc[0][r] + (float)xv[jt * 4 + 0][r];
                float gf = acc[1][r] + (float)xv[jt * 4 + 1][r];
                float gg = acc[2][r] + (float)xv[jt * 4 + 2][r];
                float go = acc[3][r] + (float)xv[jt * 4 + 3][r];
                float cc = sigf(gf) * c_[jt][r] + sigf(gi) * tanhf_(gg);
                c_[jt][r] = cc;
                float hh = sigf(go) * tanhf_(cc);
                if (t < len_[r]) pa[jt][r] += hh;
                int b = 4 * (l >> 4) + r;
                int j = w * 32 + jt * 16 + (l & 15);
                hbuf[cur ^ 1][j >> 5][(((j & 31) >> 3) << 4) + b][j & 7] = (_Float16)hh;
            }
        }
        __syncthreads();
        cur ^= 1;
    }

#pragma unroll
    for (int jt = 0; jt < 2; jt++)
#pragma unroll
        for (int r = 0; r < 4; r++) {
            int b = 4 * (l >> 4) + r;
            int j = w * 32 + jt * 16 + (l & 15);
            pooled[(size_t)(bg * 16 + b) * HH + j] = pa[jt][r] / (float)len_[r];
        }
}

// ============ head: unchanged ============
__global__ __launch_bounds__(256) void head_kernel(
    const float* __restrict__ pooled, const float* __restrict__ Wp1,
    const float* __restrict__ bp1, const float* __restrict__ Wp2,
    const float* __restrict__ bp2, float* __restrict__ y0ws)
{
    __shared__ __align__(16) float psh[HH];
    __shared__ __align__(16) float rsh[HH];
    int tid = threadIdx.x, b = blockIdx.x;
    psh[tid] = pooled[(size_t)b * HH + tid];
    __syncthreads();
    float a = bp1[tid];
    const float* wr = Wp1 + (size_t)tid * HH;
#pragma unroll 8
    for (int k = 0; k < HH; k += 4) {
        float4 w = *(const float4*)(wr + k);
        a += psh[k] * w.x + psh[k + 1] * w.y + psh[k + 2] * w.z + psh[k + 3] * w.w;
    }
    rsh[tid] = fmaxf(a, 0.f);
    __syncthreads();
    if (tid < DD) {
        float acc = bp2[tid];
        const float* w2 = Wp2 + (size_t)tid * HH;
#pragma unroll 8
        for (int h = 0; h < HH; h += 4) {
            float4 w = *(const float4*)(w2 + h);
            acc += rsh[h] * w.x + rsh[h + 1] * w.y + rsh[h + 2] * w.z + rsh[h + 3] * w.w;
        }
        y0ws[(size_t)b * DD + tid] = acc;
    }
}

// ============ ODE v2 (r5-validated, best measured ~950us): fdot2, 512 indep blocks ============
// 512 blocks x 256 thr = 2 blocks/CU co-resident; independent blocks fill each other's
// barrier/LDS stalls (the only occupancy trick that helped this latency chain: r7/r8/r12).
__global__ __launch_bounds__(256) void ode_kernel(
    const float* __restrict__ y0ws, const u32* __restrict__ Wd1p,
    const float* __restrict__ bd1, const u32* __restrict__ Wd2p,
    const float* __restrict__ bd2, const float* __restrict__ ltime,
    const float* __restrict__ lfeat, const float* __restrict__ lmask,
    float* __restrict__ pred, float* __restrict__ losso)
{
    __shared__ __align__(16) u32 ysh16[32];    // packed f16 y pairs
    __shared__ __align__(16) u32 hsh16[128];   // packed f16 h pairs
    int tid = threadIdx.x;
    int wv = tid >> 6, lq = tid & 63;
    int o = (wv << 4) + (lq & 15), q = lq >> 4;
    int b = blockIdx.x;
    u32 w1p[32], w2p[32];
#pragma unroll
    for (int j = 0; j < 32; j++) w1p[j] = Wd1p[j * 256 + tid];
#pragma unroll
    for (int j = 0; j < 32; j++) w2p[j] = Wd2p[j * 256 + tid];
    float bd1t = bd1[tid];
    float bd2o = bd2[o];
    float y = y0ws[(size_t)b * DD + o];
    if (q == 0) {
        size_t idx = ((size_t)b * TT + 0) * DD + o;
        pred[idx] = y;
        float lf = lfeat[idx], lm = lmask[idx];
        losso[idx] = (y - lf) * (y - lf) * (1.f - lm);
    }
    float kp = 0.f;
    for (int iv = 0; iv < TT - 1; iv++) {
        float t0 = ltime[(size_t)b * TT + iv], t1 = ltime[(size_t)b * TT + iv + 1];
        float dt = (t1 - t0) * 0.125f;
        for (int ss = 0; ss < 8; ss++) {
            float sacc = 0.f;
            kp = 0.f;
            const float AE[4] = {0.f, 0.5f, 0.5f, 1.f};
            const float WE[4] = {1.f, 2.f, 2.f, 1.f};
#pragma unroll
            for (int e = 0; e < 4; e++) {
                float yp = y + AE[e] * dt * kp;         // all lanes (y, kp replicated per q)
                float ypo = __shfl_xor(yp, 1);
                if (lq < 16 && !(lq & 1))
                    ysh16[8 * wv + (lq >> 1)] = pkrtz(yp, ypo);
                __syncthreads();
                float a0 = 0.f, a1 = 0.f, a2 = 0.f, a3 = 0.f;
                const uint4* yv4 = (const uint4*)ysh16;
#pragma unroll
                for (int j4 = 0; j4 < 8; j4++) {
                    uint4 yv = yv4[j4];
                    a0 = fdot2u(w1p[4 * j4 + 0], yv.x, a0);
                    a1 = fdot2u(w1p[4 * j4 + 1], yv.y, a1);
                    a2 = fdot2u(w1p[4 * j4 + 2], yv.z, a2);
                    a3 = fdot2u(w1p[4 * j4 + 3], yv.w, a3);
                }
                float hv = fmaxf(bd1t + ((a0 + a1) + (a2 + a3)), 0.f);
                float hvo = __shfl_xor(hv, 1);
                if (!(tid & 1))
                    hsh16[tid >> 1] = pkrtz(hv, hvo);
                __syncthreads();
                float b0 = 0.f, b1 = 0.f, b2 = 0.f, b3 = 0.f;
                const uint4* hv4 = (const uint4*)&hsh16[q << 5];
#pragma unroll
                for (int j4 = 0; j4 < 8; j4++) {
                    uint4 hh = hv4[j4];
                    b0 = fdot2u(w2p[4 * j4 + 0], hh.x, b0);
                    b1 = fdot2u(w2p[4 * j4 + 1], hh.y, b1);
                    b2 = fdot2u(w2p[4 * j4 + 2], hh.z, b2);
                    b3 = fdot2u(w2p[4 * j4 + 3], hh.w, b3);
                }
                float p = (b0 + b1) + (b2 + b3);
                p += __shfl_xor(p, 16);
                p += __shfl_xor(p, 32);
                float kv = p + bd2o;
                kp = kv;
                sacc += WE[e] * kv;
            }
            y += dt * (1.f / 6.f) * sacc;
        }
        if (q == 0) {
            size_t idx = ((size_t)b * TT + iv + 1) * DD + o;
            pred[idx] = y;
            float lf = lfeat[idx], lm = lmask[idx];
            losso[idx] = (y - lf) * (y - lf) * (1.f - lm);
        }
    }
}

extern "C" void kernel_launch(void* const* d_in, const int* in_sizes, int n_in,
                              void* d_out, int out_size, void* d_ws, size_t ws_size,
                              hipStream_t stream)
{
    const float* x      = (const float*)d_in[0];
    const int* lengths  = (const int*)d_in[1];
    const float* lfeat  = (const float*)d_in[2];
    const float* ltime  = (const float*)d_in[3];
    const float* lmask  = (const float*)d_in[4];
    const float* W_ih   = (const float*)d_in[5];
    const float* W_hh   = (const float*)d_in[6];
    const float* b_ih   = (const float*)d_in[7];
    const float* b_hh   = (const float*)d_in[8];
    const float* Wp1    = (const float*)d_in[9];
    const float* bp1    = (const float*)d_in[10];
    const float* Wp2    = (const float*)d_in[11];
    const float* bp2    = (const float*)d_in[12];
    const float* Wd1    = (const float*)d_in[13];
    const float* bd1    = (const float*)d_in[14];
    const float* Wd2    = (const float*)d_in[15];
    const float* bd2    = (const float*)d_in[16];

    float* pred  = (float*)d_out;
    float* losso = pred + (size_t)BB * TT * DD;

    char* ws = (char*)d_ws;
    h4*       xwf    = (h4*)(ws + 0);                  // 268435456
    h4*       BhhV   = (h4*)(ws + 268435456);          //    262144
    h4*       BhhL   = (h4*)(ws + 268697600);          //    131072
    h4*       BhhS   = (h4*)(ws + 268828672);          //    131072
    _Float16* Bih    = (_Float16*)(ws + 268959744);    //    327680
    float*    pooled = (float*)(ws + 269287424);       //    524288
    float*    y0ws   = (float*)(ws + 269811712);       //    131072
    u32*      Wd1p   = (u32*)(ws + 269942784);         //     32768
    u32*      Wd2p   = (u32*)(ws + 269975552);         //     32768

    prep_kernel<<<480, 256, 0, stream>>>(W_hh, W_ih, Wd1, Wd2, BhhV, BhhL, BhhS, Bih, Wd1p, Wd2p);
    xw_kernel<<<2048, 256, 0, stream>>>(x, Bih, b_ih, b_hh, xwf);
    lstm_kernel<<<32, 512, 0, stream>>>((const h8*)BhhV, (const h8*)BhhL, (const h8*)BhhS,
                                        xwf, lengths, pooled);
    head_kernel<<<BB, 256, 0, stream>>>(pooled, Wp1, bp1, Wp2, bp2, y0ws);
    ode_kernel<<<512, 256, 0, stream>>>(y0ws, Wd1p, bd1, Wd2p, bd2, ltime, lfeat, lmask, pred, losso);
}